// Round 5
// baseline (695.165 us; speedup 1.0000x reference)
//
#include <hip/hip_runtime.h>
#include <hip/hip_bf16.h>

// Problem constants: D=1024, N=4096, K=16, M = N*K = 65536, K-dim main = 2048

typedef __attribute__((ext_vector_type(4))) float f32x4;
typedef __attribute__((ext_vector_type(8))) short bf16x8;

__device__ __forceinline__ ushort f2bf(float f) {
  unsigned b = __builtin_bit_cast(unsigned, f);
  b += 0x7FFFu + ((b >> 16) & 1u);   // RNE
  return (ushort)(b >> 16);
}
__device__ __forceinline__ unsigned pk2(float a, float b) {
  return (unsigned)f2bf(a) | ((unsigned)f2bf(b) << 16);
}

// LDS XOR swizzle for the A tile (verified in passing R1/R4 kernels)
__device__ __forceinline__ unsigned swz(unsigned a) {
  return a ^ (((a >> 7) & 3u) << 4);
}

__device__ __forceinline__ bf16x8 cvt8(const float* p) {
  f32x4 a = *(const f32x4*)p;
  f32x4 b = *(const f32x4*)(p + 4);
  bf16x8 r;
  r[0] = (short)f2bf(a[0]); r[1] = (short)f2bf(a[1]);
  r[2] = (short)f2bf(a[2]); r[3] = (short)f2bf(a[3]);
  r[4] = (short)f2bf(b[0]); r[5] = (short)f2bf(b[1]);
  r[6] = (short)f2bf(b[2]); r[7] = (short)f2bf(b[3]);
  return r;
}

// ---------------------------------------------------------------------------
// prep: LDS tile-transpose weight packer (verified green in R4).
// mode 0 (bid<512):  Bmain packed layout: flat = kt*32768 + wg*4096 + c*8 + m,
//                    chunk c = nf*64 + lane; value = Wl[1024+kt*32+(lane>>4)*8+m]
//                                                      [wg*128+nf*16+(lane&15)]
// mode 1 (512..768): Bk1 layout [kt][nn][q*8+m] from Wl rows 0..1023
// mode 2 (768..1280): Bgate same layout from Wg rows kt*32 (+ row+1024 summed
//                    when kt>=32)
// ---------------------------------------------------------------------------
__global__ __launch_bounds__(256) void prep_kernel(
    const float* __restrict__ Wl, const float* __restrict__ Wg,
    ushort* __restrict__ Bmain, ushort* __restrict__ Bk1,
    ushort* __restrict__ Bgate) {
  __shared__ float L[32][129];
  int t = threadIdx.x;
  int bid = blockIdx.x;
  const float* src; int row0, mode, kt, wg; ushort* dst;
  if (bid < 512)      { mode = 0; kt = bid >> 3;        wg = bid & 7; src = Wl; row0 = 1024 + kt * 32; dst = Bmain; }
  else if (bid < 768) { mode = 1; kt = (bid - 512) >> 3; wg = (bid - 512) & 7; src = Wl; row0 = kt * 32; dst = Bk1; }
  else                { mode = 2; kt = (bid - 768) >> 3; wg = (bid - 768) & 7; src = Wg; row0 = kt * 32; dst = Bgate; }
  int col0 = wg * 128;
  bool dosum = (mode == 2) && (kt >= 32);
#pragma unroll
  for (int p = 0; p < 4; ++p) {
    int r = p * 8 + (t >> 5), c = (t & 31) * 4;
    const float* sp = src + (size_t)(row0 + r) * 1024 + col0 + c;
    f32x4 v = *(const f32x4*)sp;
    if (dosum) { f32x4 v2 = *(const f32x4*)(sp + (size_t)1024 * 1024); v += v2; }
    L[r][c] = v[0]; L[r][c + 1] = v[1]; L[r][c + 2] = v[2]; L[r][c + 3] = v[3];
  }
  __syncthreads();
  if (mode == 0) {
    for (int c = t; c < 512; c += 256) {
      int nf = c >> 6, lane = c & 63, lr_ = lane & 15, lh_ = lane >> 4;
      bf16x8 o;
#pragma unroll
      for (int m = 0; m < 8; ++m) o[m] = (short)f2bf(L[lh_ * 8 + m][nf * 16 + lr_]);
      *(bf16x8*)(dst + (size_t)kt * 32768 + wg * 4096 + c * 8) = o;
    }
  } else {
    for (int c = t; c < 512; c += 256) {
      int nn = c >> 2, q = c & 3;
      bf16x8 o;
#pragma unroll
      for (int m = 0; m < 8; ++m) o[m] = (short)f2bf(L[q * 8 + m][nn]);
      *(bf16x8*)(dst + (size_t)kt * 32768 + (size_t)(wg * 128 + nn) * 32 + q * 8) = o;
    }
  }
}

// ---------------------------------------------------------------------------
// gemm_small: C = act(A_f32 @ Bpack + bias). 64x128 tile, 4 waves (2x2),
// wave tile 32x64. grid (M/64, 8) = 512 blocks -> 2 blocks/CU. (green in R4)
// ---------------------------------------------------------------------------
template <int NKT, int NSPLIT, int ACT>
__global__ __launch_bounds__(256) void gemm_small(
    const float* __restrict__ A0, const float* __restrict__ A1,
    const ushort* __restrict__ Bp, const float* __restrict__ bias,
    float* __restrict__ Cout) {
  int tid = threadIdx.x, l = tid & 63, wid = tid >> 6;
  int wm = wid & 1, wn = wid >> 1;
  int mbase = blockIdx.x * 64 + wm * 32;
  int nbase = blockIdx.y * 128 + wn * 64;
  int lr = l & 15, lh = l >> 4;
  f32x4 acc[2][4] = {};
#pragma unroll 1
  for (int kt = 0; kt < NKT; ++kt) {
    const float* As = (kt < NSPLIT) ? A0 : A1;
    int ke = ((kt < NSPLIT) ? kt : kt - NSPLIT) * 32 + lh * 8;
    bf16x8 af[2];
#pragma unroll
    for (int mf = 0; mf < 2; ++mf)
      af[mf] = cvt8(As + (size_t)(mbase + mf * 16 + lr) * 1024 + ke);
    bf16x8 bf[4];
#pragma unroll
    for (int nf = 0; nf < 4; ++nf)
      bf[nf] = *(const bf16x8*)(Bp + (size_t)kt * 32768 +
                                (size_t)(nbase + nf * 16 + lr) * 32 + lh * 8);
#pragma unroll
    for (int nf = 0; nf < 4; ++nf)
#pragma unroll
      for (int mf = 0; mf < 2; ++mf)
        acc[mf][nf] = __builtin_amdgcn_mfma_f32_16x16x32_bf16(
            af[mf], bf[nf], acc[mf][nf], 0, 0, 0);
  }
#pragma unroll
  for (int nf = 0; nf < 4; ++nf) {
    int col = nbase + nf * 16 + lr;
    float bs = bias[col];
#pragma unroll
    for (int mf = 0; mf < 2; ++mf)
#pragma unroll
      for (int j = 0; j < 4; ++j) {
        int row = mbase + mf * 16 + lh * 4 + j;
        float v = acc[mf][nf][j] + bs;
        if (ACT == 1) v = 1.0f / (1.0f + expf(-v));
        Cout[(size_t)row * 1024 + col] = v;
      }
  }
}

// ---------------------------------------------------------------------------
// main fused kernel — R4 green structure with K super-iterations:
// 4 K-steps (span) per __syncthreads instead of 1. A is staged 4 tiles/span
// into a double-buffered 32KB LDS region; next-span A global loads issue
// right after the barrier (HBM latency hidden under 128 MFMAs); within a
// span there is NO barrier so B register loads pipeline across the 4 steps.
// Per block: 64 M-rows (= 4 tokens x 16 k) x 1024 cols, 8 waves (1x8).
// Epilogue (unchanged): +t_part, exact GELU, LayerNorm, softmax-weighted sum.
// ---------------------------------------------------------------------------
__global__ __launch_bounds__(512, 2) void main_kernel(
    const float* __restrict__ routed, const float* __restrict__ delta,
    const float* __restrict__ simrow, const ushort* __restrict__ Bmain,
    const float* __restrict__ tpart, const float* __restrict__ gamma,
    const float* __restrict__ beta, float* __restrict__ out_arg) {
  __shared__ ushort Ab[2][4][2048];     // 2 span-buffers x 4 tiles x 4KB (swz)
  __shared__ float ldsG[1024], ldsB2[1024];
  __shared__ float ldsW[64];            // softmax weights for 4 tokens x 16 k
  __shared__ float lnS[64 * 8], lnQ[64 * 8];

  int tid = threadIdx.x, l = tid & 63, wid = tid >> 6;
  int bx = blockIdx.x;                  // tokens bx*4 .. bx*4+3
  int lr = l & 15, lh = l >> 4;

  for (int i = tid; i < 1024; i += 512) { ldsG[i] = gamma[i]; ldsB2[i] = beta[i]; }
  if (tid < 4) {                        // softmax over K=16 for token bx*4+tid
    int n = bx * 4 + tid;
    float sv[16], mx = -1e30f;
#pragma unroll
    for (int j = 0; j < 16; ++j) { sv[j] = simrow[n * 16 + j]; mx = fmaxf(mx, sv[j]); }
    float s = 0.f;
#pragma unroll
    for (int j = 0; j < 16; ++j) { sv[j] = expf(sv[j] - mx); s += sv[j]; }
    float inv = 1.0f / s;
#pragma unroll
    for (int j = 0; j < 16; ++j) ldsW[tid * 16 + j] = sv[j] * inv;
  }

  // A staging geometry (verified): thread stages 8 bytes of each 4KB tile
  const int arow = tid >> 3;                 // 0..63
  const int akoff = (tid & 7) * 4;           // f32 element offset in 32-k tile
  const size_t am = (size_t)(bx * 64 + arow) * 1024 + akoff;
  const unsigned adst = swz((unsigned)tid * 8);

  // ---- prologue: stage span 0 (tiles kt=0..3, all routed) into Ab[0] ----
#pragma unroll
  for (int u = 0; u < 4; ++u) {
    f32x4 v = *(const f32x4*)(routed + am + (size_t)u * 32);
    uint2 w; w.x = pk2(v[0], v[1]); w.y = pk2(v[2], v[3]);
    *(uint2*)((char*)Ab[0][u] + adst) = w;
  }
  __syncthreads();

  f32x4 acc[4][8] = {};
#pragma unroll 1
  for (int s = 0; s < 16; ++s) {
    int cb = s & 1;
    // prefetch next span's 4 A-chunks (HBM latency hides under this span)
    f32x4 av[4];
    bool have = (s + 1) < 16;
    if (have) {
#pragma unroll
      for (int u = 0; u < 4; ++u) {
        int kt2 = (s + 1) * 4 + u;
        const float* asrc = (kt2 < 32) ? routed : delta;
        av[u] = *(const f32x4*)(asrc + am + (size_t)(kt2 & 31) * 32);
      }
    }
    // 4 compute K-steps, no barrier in between (B loads pipeline freely)
#pragma unroll
    for (int u = 0; u < 4; ++u) {
      int kt = s * 4 + u;
      bf16x8 bf[8];
#pragma unroll
      for (int nf = 0; nf < 8; ++nf)
        bf[nf] = *(const bf16x8*)(Bmain + (size_t)kt * 32768 +
                                  (size_t)wid * 4096 + (size_t)nf * 512 + l * 8);
      bf16x8 af[4];
#pragma unroll
      for (int mf = 0; mf < 4; ++mf) {
        unsigned a = (unsigned)(mf * 16 + lr) * 64 + (unsigned)lh * 16;
        af[mf] = *(const bf16x8*)((const char*)Ab[cb][u] + swz(a));
      }
#pragma unroll
      for (int nf = 0; nf < 8; ++nf)
#pragma unroll
        for (int mf = 0; mf < 4; ++mf)
          acc[mf][nf] = __builtin_amdgcn_mfma_f32_16x16x32_bf16(
              af[mf], bf[nf], acc[mf][nf], 0, 0, 0);
    }
    // write next span's tiles into the alternate buffer, then one barrier
    if (have) {
#pragma unroll
      for (int u = 0; u < 4; ++u) {
        uint2 w; w.x = pk2(av[u][0], av[u][1]); w.y = pk2(av[u][2], av[u][3]);
        *(uint2*)((char*)Ab[cb ^ 1][u] + adst) = w;
      }
    }
    __syncthreads();
  }

  // ---- fused epilogue (unchanged from green R4) ----
  // acc[mf][nf][j]: local row mf*16 + lh*4 + j (= token mf, k = lh*4+j),
  //                 col wid*128 + nf*16 + lr
  const float inv_d = 1.0f / 1024.0f;
  float gam[8], bet[8];
#pragma unroll
  for (int nf = 0; nf < 8; ++nf) {
    int c = wid * 128 + nf * 16 + lr;
    gam[nf] = ldsG[c]; bet[nf] = ldsB2[c];
  }
#pragma unroll
  for (int mf = 0; mf < 4; ++mf) {
    int tokrow = bx * 4 + mf;
    float s[4] = {0, 0, 0, 0}, q[4] = {0, 0, 0, 0};
#pragma unroll
    for (int nf = 0; nf < 8; ++nf) {
      float tp = tpart[(size_t)tokrow * 1024 + wid * 128 + nf * 16 + lr];
#pragma unroll
      for (int j = 0; j < 4; ++j) {
        float h = acc[mf][nf][j] + tp;
        float g = 0.5f * h * (1.0f + erff(h * 0.70710678118654752f));
        acc[mf][nf][j] = g;
        s[j] += g; q[j] += g * g;
      }
    }
#pragma unroll
    for (int j = 0; j < 4; ++j) {
#pragma unroll
      for (int d = 1; d <= 8; d <<= 1) {
        s[j] += __shfl_xor(s[j], d, 64);
        q[j] += __shfl_xor(q[j], d, 64);
      }
    }
    if (lr == 0) {
#pragma unroll
      for (int j = 0; j < 4; ++j) {
        int row = mf * 16 + lh * 4 + j;
        lnS[row * 8 + wid] = s[j];
        lnQ[row * 8 + wid] = q[j];
      }
    }
  }
  __syncthreads();
#pragma unroll
  for (int mf = 0; mf < 4; ++mf) {
    float mu[4], rs[4], wk[4];
#pragma unroll
    for (int j = 0; j < 4; ++j) {
      int row = mf * 16 + lh * 4 + j;
      float S = 0.f, Q = 0.f;
#pragma unroll
      for (int w = 0; w < 8; ++w) { S += lnS[row * 8 + w]; Q += lnQ[row * 8 + w]; }
      float m_ = S * inv_d;
      mu[j] = m_;
      rs[j] = rsqrtf(Q * inv_d - m_ * m_ + 1e-5f);
      wk[j] = ldsW[row];
    }
#pragma unroll
    for (int nf = 0; nf < 8; ++nf) {
      float ws = 0.f;
#pragma unroll
      for (int j = 0; j < 4; ++j) {
        float y = (acc[mf][nf][j] - mu[j]) * rs[j] * gam[nf] + bet[nf];
        ws += wk[j] * y;
      }
      ws += __shfl_xor(ws, 16, 64);
      ws += __shfl_xor(ws, 32, 64);
      if (lh == 0)
        out_arg[(size_t)(bx * 4 + mf) * 1024 + wid * 128 + nf * 16 + lr] = ws;
    }
  }
}

// ---------------------------------------------------------------------------
extern "C" void kernel_launch(void* const* d_in, const int* in_sizes, int n_in,
                              void* d_out, int out_size, void* d_ws, size_t ws_size,
                              hipStream_t stream) {
  const float* token  = (const float*)d_in[0];
  const float* routed = (const float*)d_in[1];
  const float* simrow = (const float*)d_in[2];
  const float* delta  = (const float*)d_in[3];
  const float* Wl     = (const float*)d_in[4];
  const float* bl     = (const float*)d_in[5];
  const float* gamma  = (const float*)d_in[6];
  const float* beta   = (const float*)d_in[7];
  const float* Wg     = (const float*)d_in[8];
  const float* bg     = (const float*)d_in[9];

  char* ws = (char*)d_ws;
  ushort* Bmain = (ushort*)(ws);                         // 4 MB
  ushort* Bk1   = (ushort*)(ws + (4u << 20));            // 2 MB
  ushort* Bgate = (ushort*)(ws + (6u << 20));            // 4 MB
  float*  tpart = (float*)(ws + (10u << 20));            // 16 MB

  float* out_arg  = (float*)d_out;
  float* out_gate = out_arg + (size_t)4096 * 1024;

  prep_kernel<<<1280, 256, 0, stream>>>(Wl, Wg, Bmain, Bk1, Bgate);
  gemm_small<32, 32, 0><<<dim3(64, 8), 256, 0, stream>>>(
      token, token, Bk1, bl, tpart);
  main_kernel<<<1024, 512, 0, stream>>>(
      routed, delta, simrow, Bmain, tpart, gamma, beta, out_arg);
  gemm_small<64, 32, 1><<<dim3(64, 8), 256, 0, stream>>>(
      token, out_arg, Bgate, bg, out_gate);
}

// Round 6
// 615.268 us; speedup vs baseline: 1.1299x; 1.1299x over previous
//
#include <hip/hip_runtime.h>
#include <hip/hip_bf16.h>

// Problem constants: D=1024, N=4096, K=16, M = N*K = 65536, K-dim main = 2048

typedef __attribute__((ext_vector_type(4))) float f32x4;
typedef __attribute__((ext_vector_type(8))) short bf16x8;

__device__ __forceinline__ ushort f2bf(float f) {
  unsigned b = __builtin_bit_cast(unsigned, f);
  b += 0x7FFFu + ((b >> 16) & 1u);   // RNE
  return (ushort)(b >> 16);
}
__device__ __forceinline__ unsigned pk2(float a, float b) {
  return (unsigned)f2bf(a) | ((unsigned)f2bf(b) << 16);
}

// LDS XOR swizzle for the A tile (verified in passing R1/R4 kernels)
__device__ __forceinline__ unsigned swz(unsigned a) {
  return a ^ (((a >> 7) & 3u) << 4);
}

__device__ __forceinline__ bf16x8 cvt8(const float* p) {
  f32x4 a = *(const f32x4*)p;
  f32x4 b = *(const f32x4*)(p + 4);
  bf16x8 r;
  r[0] = (short)f2bf(a[0]); r[1] = (short)f2bf(a[1]);
  r[2] = (short)f2bf(a[2]); r[3] = (short)f2bf(a[3]);
  r[4] = (short)f2bf(b[0]); r[5] = (short)f2bf(b[1]);
  r[6] = (short)f2bf(b[2]); r[7] = (short)f2bf(b[3]);
  return r;
}

#define GLOAD_LDS(G, S) __builtin_amdgcn_global_load_lds( \
    (const __attribute__((address_space(1))) void*)(G),   \
    (__attribute__((address_space(3))) void*)(S), 16, 0, 0)

// ---------------------------------------------------------------------------
// prep: LDS tile-transpose weight packer (verified green in R4).
// mode 0 (bid<512):  Bmain packed layout: flat = kt*32768 + wg*4096 + c*8 + m,
//                    chunk c = nf*64 + lane; value = Wl[1024+kt*32+(lane>>4)*8+m]
//                                                      [wg*128+nf*16+(lane&15)]
// mode 1 (512..768): Bk1 layout [kt][nn][q*8+m] from Wl rows 0..1023
// mode 2 (768..1280): Bgate same layout from Wg rows kt*32 (+ row+1024 summed
//                    when kt>=32)
// ---------------------------------------------------------------------------
__global__ __launch_bounds__(256) void prep_kernel(
    const float* __restrict__ Wl, const float* __restrict__ Wg,
    ushort* __restrict__ Bmain, ushort* __restrict__ Bk1,
    ushort* __restrict__ Bgate) {
  __shared__ float L[32][129];
  int t = threadIdx.x;
  int bid = blockIdx.x;
  const float* src; int row0, mode, kt, wg; ushort* dst;
  if (bid < 512)      { mode = 0; kt = bid >> 3;        wg = bid & 7; src = Wl; row0 = 1024 + kt * 32; dst = Bmain; }
  else if (bid < 768) { mode = 1; kt = (bid - 512) >> 3; wg = (bid - 512) & 7; src = Wl; row0 = kt * 32; dst = Bk1; }
  else                { mode = 2; kt = (bid - 768) >> 3; wg = (bid - 768) & 7; src = Wg; row0 = kt * 32; dst = Bgate; }
  int col0 = wg * 128;
  bool dosum = (mode == 2) && (kt >= 32);
#pragma unroll
  for (int p = 0; p < 4; ++p) {
    int r = p * 8 + (t >> 5), c = (t & 31) * 4;
    const float* sp = src + (size_t)(row0 + r) * 1024 + col0 + c;
    f32x4 v = *(const f32x4*)sp;
    if (dosum) { f32x4 v2 = *(const f32x4*)(sp + (size_t)1024 * 1024); v += v2; }
    L[r][c] = v[0]; L[r][c + 1] = v[1]; L[r][c + 2] = v[2]; L[r][c + 3] = v[3];
  }
  __syncthreads();
  if (mode == 0) {
    for (int c = t; c < 512; c += 256) {
      int nf = c >> 6, lane = c & 63, lr_ = lane & 15, lh_ = lane >> 4;
      bf16x8 o;
#pragma unroll
      for (int m = 0; m < 8; ++m) o[m] = (short)f2bf(L[lh_ * 8 + m][nf * 16 + lr_]);
      *(bf16x8*)(dst + (size_t)kt * 32768 + wg * 4096 + c * 8) = o;
    }
  } else {
    for (int c = t; c < 512; c += 256) {
      int nn = c >> 2, q = c & 3;
      bf16x8 o;
#pragma unroll
      for (int m = 0; m < 8; ++m) o[m] = (short)f2bf(L[q * 8 + m][nn]);
      *(bf16x8*)(dst + (size_t)kt * 32768 + (size_t)(wg * 128 + nn) * 32 + q * 8) = o;
    }
  }
}

// ---------------------------------------------------------------------------
// gemm_small: C = act(A_f32 @ Bpack + bias). 64x128 tile, 4 waves (2x2),
// wave tile 32x64. grid (M/64, 8) = 512 blocks -> 2 blocks/CU. (green in R4)
// ---------------------------------------------------------------------------
template <int NKT, int NSPLIT, int ACT>
__global__ __launch_bounds__(256) void gemm_small(
    const float* __restrict__ A0, const float* __restrict__ A1,
    const ushort* __restrict__ Bp, const float* __restrict__ bias,
    float* __restrict__ Cout) {
  int tid = threadIdx.x, l = tid & 63, wid = tid >> 6;
  int wm = wid & 1, wn = wid >> 1;
  int mbase = blockIdx.x * 64 + wm * 32;
  int nbase = blockIdx.y * 128 + wn * 64;
  int lr = l & 15, lh = l >> 4;
  f32x4 acc[2][4] = {};
#pragma unroll 1
  for (int kt = 0; kt < NKT; ++kt) {
    const float* As = (kt < NSPLIT) ? A0 : A1;
    int ke = ((kt < NSPLIT) ? kt : kt - NSPLIT) * 32 + lh * 8;
    bf16x8 af[2];
#pragma unroll
    for (int mf = 0; mf < 2; ++mf)
      af[mf] = cvt8(As + (size_t)(mbase + mf * 16 + lr) * 1024 + ke);
    bf16x8 bf[4];
#pragma unroll
    for (int nf = 0; nf < 4; ++nf)
      bf[nf] = *(const bf16x8*)(Bp + (size_t)kt * 32768 +
                                (size_t)(nbase + nf * 16 + lr) * 32 + lh * 8);
#pragma unroll
    for (int nf = 0; nf < 4; ++nf)
#pragma unroll
      for (int mf = 0; mf < 2; ++mf)
        acc[mf][nf] = __builtin_amdgcn_mfma_f32_16x16x32_bf16(
            af[mf], bf[nf], acc[mf][nf], 0, 0, 0);
  }
#pragma unroll
  for (int nf = 0; nf < 4; ++nf) {
    int col = nbase + nf * 16 + lr;
    float bs = bias[col];
#pragma unroll
    for (int mf = 0; mf < 2; ++mf)
#pragma unroll
      for (int j = 0; j < 4; ++j) {
        int row = mbase + mf * 16 + lh * 4 + j;
        float v = acc[mf][nf][j] + bs;
        if (ACT == 1) v = 1.0f / (1.0f + expf(-v));
        Cout[(size_t)row * 1024 + col] = v;
      }
  }
}

// ---------------------------------------------------------------------------
// main fused kernel, counted-vmcnt glds pipeline (R2 architecture, FIXED
// buffer sizes: one B K-step tile = 1024 cols x 32 k x 2B = 64 KB, not 32 KB
// -- R2 declared 32 KB and waves 4-7 overwrote B1/A0/A1 => corruption).
// Per block: 64 M-rows (4 tokens x 16 k) x 1024 cols, 8 waves (1x8).
// B: global_load_lds -> per-wave-private 8KB slice of 64KB tile, dbuf,
//    staged 1 iter ahead; counted vmcnt(1) leaves A prefetch in flight.
// A: f32 global -> reg -> cvt bf16 -> swizzled LDS dbuf (cooperative).
// Dyn smem 139520 B: B0 64K | B1 64K | A0 4K | A1 4K | ldsW 256B.
// lnS/lnQ overlay B0 in the epilogue (B0 dead after iter 62's compute).
// ---------------------------------------------------------------------------
#define STAGE_B(KTN, BN) do {                                             \
  const ushort* bg_ = Bmain + (size_t)(KTN) * 32768 + (size_t)wid * 4096; \
  char* ld_ = (char*)(BN) + (size_t)wid * 8192;                           \
  _Pragma("unroll")                                                       \
  for (int i_ = 0; i_ < 8; ++i_)                                          \
    GLOAD_LDS(bg_ + i_ * 512 + l * 8, ld_ + i_ * 1024);                   \
} while (0)

#define COMPUTE_TILE(BC, AC) do {                                         \
  bf16x8 af_[4], bf_[8];                                                  \
  _Pragma("unroll")                                                       \
  for (int mf = 0; mf < 4; ++mf) {                                        \
    unsigned a_ = (unsigned)(mf * 16 + lr) * 64 + (unsigned)lh * 16;      \
    af_[mf] = *(const bf16x8*)((const char*)(AC) + swz(a_)); }            \
  _Pragma("unroll")                                                       \
  for (int nf = 0; nf < 8; ++nf)                                          \
    bf_[nf] = *(const bf16x8*)((const char*)(BC) + (size_t)wid * 8192 +   \
                               nf * 1024 + l * 16);                       \
  _Pragma("unroll")                                                       \
  for (int nf = 0; nf < 8; ++nf)                                          \
    _Pragma("unroll")                                                     \
    for (int mf = 0; mf < 4; ++mf)                                        \
      acc[mf][nf] = __builtin_amdgcn_mfma_f32_16x16x32_bf16(              \
          af_[mf], bf_[nf], acc[mf][nf], 0, 0, 0);                        \
} while (0)

#define WRITE_A(AV, AN) do {                                              \
  uint2 w_; w_.x = pk2((AV)[0], (AV)[1]); w_.y = pk2((AV)[2], (AV)[3]);   \
  *(uint2*)((char*)(AN) + adst) = w_;                                     \
} while (0)

#define BARRIER_FENCED(VMC) do {                                          \
  asm volatile("s_waitcnt lgkmcnt(0)" ::: "memory");                      \
  asm volatile("s_waitcnt vmcnt(" #VMC ")" ::: "memory");                 \
  __builtin_amdgcn_s_barrier();                                           \
  asm volatile("" ::: "memory");  /* pin LDS ops below the barrier */     \
} while (0)

#define FULL_ITER(KT, BC, BN, AC, AN, AVC, AVN) do {                      \
  STAGE_B((KT) + 1, BN);                                                  \
  asm volatile("" ::: "memory");                                          \
  { int k2_ = (KT) + 2;                                                   \
    const float* as_ = (k2_ < 32) ? routed : delta;                       \
    AVN = *(const f32x4*)(as_ + am + (size_t)(k2_ & 31) * 32); }          \
  COMPUTE_TILE(BC, AC);                                                   \
  WRITE_A(AVC, AN);                                                       \
  BARRIER_FENCED(1);                                                      \
} while (0)

__global__ __launch_bounds__(512, 2) void main_kernel(
    const float* __restrict__ routed, const float* __restrict__ delta,
    const float* __restrict__ simrow, const ushort* __restrict__ Bmain,
    const float* __restrict__ tpart, const float* __restrict__ gamma,
    const float* __restrict__ beta, float* __restrict__ out_arg) {
  extern __shared__ char smem[];
  ushort* B0 = (ushort*)smem;                   // 64 KB (one full B K-tile)
  ushort* B1 = (ushort*)(smem + 65536);         // 64 KB
  char* A0p = smem + 131072;                    // 4 KB (swizzled bf16 A tile)
  char* A1p = smem + 135168;                    // 4 KB
  float* ldsW = (float*)(smem + 139264);        // 256 B softmax weights
  float* lnS = (float*)(smem);                  // overlays B0 (epilogue only)
  float* lnQ = (float*)(smem + 2048);

  int tid = threadIdx.x, l = tid & 63, wid = tid >> 6;
  int bx = blockIdx.x;                          // tokens bx*4 .. bx*4+3
  int lr = l & 15, lh = l >> 4;

  if (tid < 4) {                                // softmax over K=16
    int n = bx * 4 + tid;
    float sv[16], mx = -1e30f;
#pragma unroll
    for (int j = 0; j < 16; ++j) { sv[j] = simrow[n * 16 + j]; mx = fmaxf(mx, sv[j]); }
    float s = 0.f;
#pragma unroll
    for (int j = 0; j < 16; ++j) { sv[j] = expf(sv[j] - mx); s += sv[j]; }
    float inv = 1.0f / s;
#pragma unroll
    for (int j = 0; j < 16; ++j) ldsW[tid * 16 + j] = sv[j] * inv;
  }

  // A staging geometry (verified): thread stages 8 bytes of the 4KB tile
  const int arow = tid >> 3;                 // 0..63
  const int akoff = (tid & 7) * 4;           // f32 element offset in 32-k tile
  const size_t am = (size_t)(bx * 64 + arow) * 1024 + akoff;
  const unsigned adst = swz((unsigned)tid * 8);

  f32x4 avA, avB;
  // ---- prologue: B(0)->B0 (glds), A(0)->lds, A(1)->avA ----
  asm volatile("" ::: "memory");
  STAGE_B(0, B0);
  asm volatile("" ::: "memory");
  f32x4 t0 = *(const f32x4*)(routed + am);
  avA = *(const f32x4*)(routed + am + 32);
  WRITE_A(t0, A0p);              // use of t0 forces drain of the older 8 glds
  BARRIER_FENCED(1);

  f32x4 acc[4][8] = {};
#pragma unroll 1
  for (int kt = 0; kt < 62; kt += 2) {
    FULL_ITER(kt,     B0, B1, A0p, A1p, avA, avB);
    FULL_ITER(kt + 1, B1, B0, A1p, A0p, avB, avA);
  }
  // ---- iter 62 (stage B(63), write A(63), full drain) ----
  STAGE_B(63, B1);
  asm volatile("" ::: "memory");
  COMPUTE_TILE(B0, A0p);
  WRITE_A(avA, A1p);
  BARRIER_FENCED(0);
  // ---- iter 63 ----
  COMPUTE_TILE(B1, A1p);

  // ---- fused epilogue: +tpart, GELU, LayerNorm, softmax-weighted K-sum ----
  const float inv_d = 1.0f / 1024.0f;
  float gam[8], bet[8];
#pragma unroll
  for (int nf = 0; nf < 8; ++nf) {
    int c = wid * 128 + nf * 16 + lr;
    gam[nf] = gamma[c]; bet[nf] = beta[c];
  }
#pragma unroll
  for (int mf = 0; mf < 4; ++mf) {
    int tokrow = bx * 4 + mf;
    float s[4] = {0, 0, 0, 0}, q[4] = {0, 0, 0, 0};
#pragma unroll
    for (int nf = 0; nf < 8; ++nf) {
      float tp = tpart[(size_t)tokrow * 1024 + wid * 128 + nf * 16 + lr];
#pragma unroll
      for (int j = 0; j < 4; ++j) {
        float h = acc[mf][nf][j] + tp;
        float g = 0.5f * h * (1.0f + erff(h * 0.70710678118654752f));
        acc[mf][nf][j] = g;
        s[j] += g; q[j] += g * g;
      }
    }
#pragma unroll
    for (int j = 0; j < 4; ++j) {
#pragma unroll
      for (int d = 1; d <= 8; d <<= 1) {
        s[j] += __shfl_xor(s[j], d, 64);
        q[j] += __shfl_xor(q[j], d, 64);
      }
    }
    if (lr == 0) {
#pragma unroll
      for (int j = 0; j < 4; ++j) {
        int row = mf * 16 + lh * 4 + j;
        lnS[row * 8 + wid] = s[j];
        lnQ[row * 8 + wid] = q[j];
      }
    }
  }
  __syncthreads();
#pragma unroll
  for (int mf = 0; mf < 4; ++mf) {
    float mu[4], rs[4], wk[4];
#pragma unroll
    for (int j = 0; j < 4; ++j) {
      int row = mf * 16 + lh * 4 + j;
      float S = 0.f, Q = 0.f;
#pragma unroll
      for (int w = 0; w < 8; ++w) { S += lnS[row * 8 + w]; Q += lnQ[row * 8 + w]; }
      float m_ = S * inv_d;
      mu[j] = m_;
      rs[j] = rsqrtf(Q * inv_d - m_ * m_ + 1e-5f);
      wk[j] = ldsW[row];
    }
#pragma unroll
    for (int nf = 0; nf < 8; ++nf) {
      float ws = 0.f;
#pragma unroll
      for (int j = 0; j < 4; ++j) {
        float y = (acc[mf][nf][j] - mu[j]) * rs[j] * gam[nf] + bet[nf];
        ws += wk[j] * y;
      }
      ws += __shfl_xor(ws, 16, 64);
      ws += __shfl_xor(ws, 32, 64);
      if (lh == 0)
        out_arg[(size_t)(bx * 4 + mf) * 1024 + wid * 128 + nf * 16 + lr] = ws;
    }
  }
}

// ---------------------------------------------------------------------------
extern "C" void kernel_launch(void* const* d_in, const int* in_sizes, int n_in,
                              void* d_out, int out_size, void* d_ws, size_t ws_size,
                              hipStream_t stream) {
  const float* token  = (const float*)d_in[0];
  const float* routed = (const float*)d_in[1];
  const float* simrow = (const float*)d_in[2];
  const float* delta  = (const float*)d_in[3];
  const float* Wl     = (const float*)d_in[4];
  const float* bl     = (const float*)d_in[5];
  const float* gamma  = (const float*)d_in[6];
  const float* beta   = (const float*)d_in[7];
  const float* Wg     = (const float*)d_in[8];
  const float* bg     = (const float*)d_in[9];

  char* ws = (char*)d_ws;
  ushort* Bmain = (ushort*)(ws);                         // 4 MB
  ushort* Bk1   = (ushort*)(ws + (4u << 20));            // 2 MB
  ushort* Bgate = (ushort*)(ws + (6u << 20));            // 4 MB
  float*  tpart = (float*)(ws + (10u << 20));            // 16 MB

  float* out_arg  = (float*)d_out;
  float* out_gate = out_arg + (size_t)4096 * 1024;

  const int SMEM = 139520;   // B0 64K | B1 64K | A0 4K | A1 4K | ldsW 256B
  hipFuncSetAttribute(reinterpret_cast<const void*>(main_kernel),
                      hipFuncAttributeMaxDynamicSharedMemorySize, SMEM);

  prep_kernel<<<1280, 256, 0, stream>>>(Wl, Wg, Bmain, Bk1, Bgate);
  gemm_small<32, 32, 0><<<dim3(64, 8), 256, 0, stream>>>(
      token, token, Bk1, bl, tpart);
  main_kernel<<<1024, 512, SMEM, stream>>>(
      routed, delta, simrow, Bmain, tpart, gamma, beta, out_arg);
  gemm_small<64, 32, 1><<<dim3(64, 8), 256, 0, stream>>>(
      token, out_arg, Bgate, bg, out_gate);
}

// Round 7
// 614.790 us; speedup vs baseline: 1.1307x; 1.0008x over previous
//
#include <hip/hip_runtime.h>
#include <hip/hip_bf16.h>

// Problem constants: D=1024, N=4096, K=16, M = N*K = 65536, K-dim main = 2048

typedef __attribute__((ext_vector_type(4))) float f32x4;
typedef __attribute__((ext_vector_type(8))) short bf16x8;

__device__ __forceinline__ ushort f2bf(float f) {
  unsigned b = __builtin_bit_cast(unsigned, f);
  b += 0x7FFFu + ((b >> 16) & 1u);   // RNE
  return (ushort)(b >> 16);
}
__device__ __forceinline__ unsigned pk2(float a, float b) {
  return (unsigned)f2bf(a) | ((unsigned)f2bf(b) << 16);
}

// LDS XOR swizzle for the A tile (verified in passing R1/R4/R6 kernels)
__device__ __forceinline__ unsigned swz(unsigned a) {
  return a ^ (((a >> 7) & 3u) << 4);
}

__device__ __forceinline__ bf16x8 cvt8(const float* p) {
  f32x4 a = *(const f32x4*)p;
  f32x4 b = *(const f32x4*)(p + 4);
  bf16x8 r;
  r[0] = (short)f2bf(a[0]); r[1] = (short)f2bf(a[1]);
  r[2] = (short)f2bf(a[2]); r[3] = (short)f2bf(a[3]);
  r[4] = (short)f2bf(b[0]); r[5] = (short)f2bf(b[1]);
  r[6] = (short)f2bf(b[2]); r[7] = (short)f2bf(b[3]);
  return r;
}

// ---------------------------------------------------------------------------
// prep: LDS tile-transpose weight packer (verified green in R4/R6).
// mode 0 (bid<512):  Bmain packed layout: flat = kt*32768 + wg*4096 + c*8 + m,
//                    chunk c = nf*64 + lane; value = Wl[1024+kt*32+(lane>>4)*8+m]
//                                                      [wg*128+nf*16+(lane&15)]
// mode 1 (512..768): Bk1 layout [kt][nn][q*8+m] from Wl rows 0..1023
// mode 2 (768..1280): Bgate same layout from Wg rows kt*32 (+ row+1024 summed
//                    when kt>=32)
// ---------------------------------------------------------------------------
__global__ __launch_bounds__(256) void prep_kernel(
    const float* __restrict__ Wl, const float* __restrict__ Wg,
    ushort* __restrict__ Bmain, ushort* __restrict__ Bk1,
    ushort* __restrict__ Bgate) {
  __shared__ float L[32][129];
  int t = threadIdx.x;
  int bid = blockIdx.x;
  const float* src; int row0, mode, kt, wg; ushort* dst;
  if (bid < 512)      { mode = 0; kt = bid >> 3;        wg = bid & 7; src = Wl; row0 = 1024 + kt * 32; dst = Bmain; }
  else if (bid < 768) { mode = 1; kt = (bid - 512) >> 3; wg = (bid - 512) & 7; src = Wl; row0 = kt * 32; dst = Bk1; }
  else                { mode = 2; kt = (bid - 768) >> 3; wg = (bid - 768) & 7; src = Wg; row0 = kt * 32; dst = Bgate; }
  int col0 = wg * 128;
  bool dosum = (mode == 2) && (kt >= 32);
#pragma unroll
  for (int p = 0; p < 4; ++p) {
    int r = p * 8 + (t >> 5), c = (t & 31) * 4;
    const float* sp = src + (size_t)(row0 + r) * 1024 + col0 + c;
    f32x4 v = *(const f32x4*)sp;
    if (dosum) { f32x4 v2 = *(const f32x4*)(sp + (size_t)1024 * 1024); v += v2; }
    L[r][c] = v[0]; L[r][c + 1] = v[1]; L[r][c + 2] = v[2]; L[r][c + 3] = v[3];
  }
  __syncthreads();
  if (mode == 0) {
    for (int c = t; c < 512; c += 256) {
      int nf = c >> 6, lane = c & 63, lr_ = lane & 15, lh_ = lane >> 4;
      bf16x8 o;
#pragma unroll
      for (int m = 0; m < 8; ++m) o[m] = (short)f2bf(L[lh_ * 8 + m][nf * 16 + lr_]);
      *(bf16x8*)(dst + (size_t)kt * 32768 + wg * 4096 + c * 8) = o;
    }
  } else {
    for (int c = t; c < 512; c += 256) {
      int nn = c >> 2, q = c & 3;
      bf16x8 o;
#pragma unroll
      for (int m = 0; m < 8; ++m) o[m] = (short)f2bf(L[q * 8 + m][nn]);
      *(bf16x8*)(dst + (size_t)kt * 32768 + (size_t)(wg * 128 + nn) * 32 + q * 8) = o;
    }
  }
}

// ---------------------------------------------------------------------------
// gemm_small: C = act(A_f32 @ Bpack + bias). 64x128 tile, 4 waves (2x2),
// wave tile 32x64. grid (M/64, 8) = 512 blocks -> 2 blocks/CU. (green)
// ---------------------------------------------------------------------------
template <int NKT, int NSPLIT, int ACT>
__global__ __launch_bounds__(256) void gemm_small(
    const float* __restrict__ A0, const float* __restrict__ A1,
    const ushort* __restrict__ Bp, const float* __restrict__ bias,
    float* __restrict__ Cout) {
  int tid = threadIdx.x, l = tid & 63, wid = tid >> 6;
  int wm = wid & 1, wn = wid >> 1;
  int mbase = blockIdx.x * 64 + wm * 32;
  int nbase = blockIdx.y * 128 + wn * 64;
  int lr = l & 15, lh = l >> 4;
  f32x4 acc[2][4] = {};
#pragma unroll 1
  for (int kt = 0; kt < NKT; ++kt) {
    const float* As = (kt < NSPLIT) ? A0 : A1;
    int ke = ((kt < NSPLIT) ? kt : kt - NSPLIT) * 32 + lh * 8;
    bf16x8 af[2];
#pragma unroll
    for (int mf = 0; mf < 2; ++mf)
      af[mf] = cvt8(As + (size_t)(mbase + mf * 16 + lr) * 1024 + ke);
    bf16x8 bf[4];
#pragma unroll
    for (int nf = 0; nf < 4; ++nf)
      bf[nf] = *(const bf16x8*)(Bp + (size_t)kt * 32768 +
                                (size_t)(nbase + nf * 16 + lr) * 32 + lh * 8);
#pragma unroll
    for (int nf = 0; nf < 4; ++nf)
#pragma unroll
      for (int mf = 0; mf < 2; ++mf)
        acc[mf][nf] = __builtin_amdgcn_mfma_f32_16x16x32_bf16(
            af[mf], bf[nf], acc[mf][nf], 0, 0, 0);
  }
#pragma unroll
  for (int nf = 0; nf < 4; ++nf) {
    int col = nbase + nf * 16 + lr;
    float bs = bias[col];
#pragma unroll
    for (int mf = 0; mf < 2; ++mf)
#pragma unroll
      for (int j = 0; j < 4; ++j) {
        int row = mbase + mf * 16 + lh * 4 + j;
        float v = acc[mf][nf][j] + bs;
        if (ACT == 1) v = 1.0f / (1.0f + expf(-v));
        Cout[(size_t)row * 1024 + col] = v;
      }
  }
}

// ---------------------------------------------------------------------------
// main fused kernel — R4-verified math with 16 waves x (64x64) wave tiles:
// 1024 threads, acc[4][4]=64 VGPR/thread, __launch_bounds__(1024,4) ->
// 4 waves/SIMD (2x the TLP of all prior rounds; that lockstep-latency was
// the measured limiter: R4/R5/R6 all ~4900cy/iter at 2 waves/SIMD).
// B: direct global->reg from packed Bmain (coalesced 16B/lane, L2-hot).
// A: f32 global -> reg -> cvt bf16 -> swizzled 4KB LDS tile, dbuf,
//    1024 threads stage 4B each.
// Epilogue: +t_part, exact GELU, LayerNorm (16-wave LDS reduce),
// softmax-weighted K-reduce -> arg_summary.
// ---------------------------------------------------------------------------
__global__ __launch_bounds__(1024, 4) void main_kernel(
    const float* __restrict__ routed, const float* __restrict__ delta,
    const float* __restrict__ simrow, const ushort* __restrict__ Bmain,
    const float* __restrict__ tpart, const float* __restrict__ gamma,
    const float* __restrict__ beta, float* __restrict__ out_arg) {
  __shared__ ushort Ab[2][2048];        // two 4KB A tiles [64][32] bf16 (swz)
  __shared__ float ldsW[64];            // softmax weights 4 tokens x 16 k
  __shared__ float lnS[64 * 16], lnQ[64 * 16];

  int tid = threadIdx.x, l = tid & 63, wid = tid >> 6;   // wid 0..15
  int bx = blockIdx.x;                  // tokens bx*4 .. bx*4+3
  int lr = l & 15, lh = l >> 4;

  if (tid < 4) {                        // softmax over K=16 for token bx*4+tid
    int n = bx * 4 + tid;
    float sv[16], mx = -1e30f;
#pragma unroll
    for (int j = 0; j < 16; ++j) { sv[j] = simrow[n * 16 + j]; mx = fmaxf(mx, sv[j]); }
    float s = 0.f;
#pragma unroll
    for (int j = 0; j < 16; ++j) { sv[j] = expf(sv[j] - mx); s += sv[j]; }
    float inv = 1.0f / s;
#pragma unroll
    for (int j = 0; j < 16; ++j) ldsW[tid * 16 + j] = sv[j] * inv;
  }

  // A staging geometry: 1024 threads x 4B of the 4KB tile.
  // thread -> row = tid>>4, f32 col pair = (tid&15)*2; logical byte = tid*4.
  const int arow = tid >> 4;
  const size_t am = (size_t)(bx * 64 + arow) * 1024 + (tid & 15) * 2;
  const unsigned adst = swz((unsigned)tid * 4);

  {  // stage kt=0 (routed)
    float2 v = *(const float2*)(routed + am);
    *(unsigned*)((char*)Ab[0] + adst) = pk2(v.x, v.y);
  }
  __syncthreads();

  // B addressing: wave wid covers cols wid*64 + nf*16 + lr; in packed layout
  // wg = wid>>1, chunk = ((wid&1)*4+nf)*64 + l  (16B per lane, coalesced)
  const ushort* bbase = Bmain + (size_t)(wid >> 1) * 4096 +
                        (size_t)(wid & 1) * 2048 + (size_t)l * 8;

  f32x4 acc[4][4] = {};
#pragma unroll 1
  for (int kt = 0; kt < 64; ++kt) {
    int cur = kt & 1;
    // prefetch next A chunk (HBM latency hides under this iter's compute)
    bool have = (kt + 1) < 64;
    float2 av;
    if (have) {
      const float* asrc = (kt + 1 < 32) ? routed : delta;
      av = *(const float2*)(asrc + am + (size_t)((kt + 1) & 31) * 32);
    }
    // B fragments direct from L2 (packed, coalesced)
    bf16x8 bf[4];
#pragma unroll
    for (int nf = 0; nf < 4; ++nf)
      bf[nf] = *(const bf16x8*)(bbase + (size_t)kt * 32768 + nf * 512);
    // A fragments from LDS (swizzled)
    bf16x8 af[4];
#pragma unroll
    for (int mf = 0; mf < 4; ++mf) {
      unsigned a = (unsigned)(mf * 16 + lr) * 64 + (unsigned)lh * 16;
      af[mf] = *(const bf16x8*)((const char*)Ab[cur] + swz(a));
    }
#pragma unroll
    for (int nf = 0; nf < 4; ++nf)
#pragma unroll
      for (int mf = 0; mf < 4; ++mf)
        acc[mf][nf] = __builtin_amdgcn_mfma_f32_16x16x32_bf16(
            af[mf], bf[nf], acc[mf][nf], 0, 0, 0);
    if (have)
      *(unsigned*)((char*)Ab[cur ^ 1] + adst) = pk2(av.x, av.y);
    __syncthreads();
  }

  // ---- fused epilogue ----
  // acc[mf][nf][j]: local row mf*16 + lh*4 + j (= token mf, k = lh*4+j),
  //                 col wid*64 + nf*16 + lr
  const float inv_d = 1.0f / 1024.0f;
  float gam[4], bet[4];
#pragma unroll
  for (int nf = 0; nf < 4; ++nf) {
    int c = wid * 64 + nf * 16 + lr;
    gam[nf] = gamma[c]; bet[nf] = beta[c];
  }
#pragma unroll
  for (int mf = 0; mf < 4; ++mf) {
    int tokrow = bx * 4 + mf;
    float s[4] = {0, 0, 0, 0}, q[4] = {0, 0, 0, 0};
#pragma unroll
    for (int nf = 0; nf < 4; ++nf) {
      float tp = tpart[(size_t)tokrow * 1024 + wid * 64 + nf * 16 + lr];
#pragma unroll
      for (int j = 0; j < 4; ++j) {
        float h = acc[mf][nf][j] + tp;
        float g = 0.5f * h * (1.0f + erff(h * 0.70710678118654752f));
        acc[mf][nf][j] = g;
        s[j] += g; q[j] += g * g;
      }
    }
#pragma unroll
    for (int j = 0; j < 4; ++j) {
#pragma unroll
      for (int d = 1; d <= 8; d <<= 1) {
        s[j] += __shfl_xor(s[j], d, 64);
        q[j] += __shfl_xor(q[j], d, 64);
      }
    }
    if (lr == 0) {
#pragma unroll
      for (int j = 0; j < 4; ++j) {
        int row = mf * 16 + lh * 4 + j;
        lnS[row * 16 + wid] = s[j];
        lnQ[row * 16 + wid] = q[j];
      }
    }
  }
  __syncthreads();
#pragma unroll
  for (int mf = 0; mf < 4; ++mf) {
    float mu[4], rs[4], wk[4];
#pragma unroll
    for (int j = 0; j < 4; ++j) {
      int row = mf * 16 + lh * 4 + j;
      float S = 0.f, Q = 0.f;
#pragma unroll
      for (int w4 = 0; w4 < 4; ++w4) {
        f32x4 vs = *(const f32x4*)&lnS[row * 16 + w4 * 4];
        f32x4 vq = *(const f32x4*)&lnQ[row * 16 + w4 * 4];
        S += vs[0] + vs[1] + vs[2] + vs[3];
        Q += vq[0] + vq[1] + vq[2] + vq[3];
      }
      float m_ = S * inv_d;
      mu[j] = m_;
      rs[j] = rsqrtf(Q * inv_d - m_ * m_ + 1e-5f);
      wk[j] = ldsW[row];
    }
#pragma unroll
    for (int nf = 0; nf < 4; ++nf) {
      float ws = 0.f;
#pragma unroll
      for (int j = 0; j < 4; ++j) {
        float y = (acc[mf][nf][j] - mu[j]) * rs[j] * gam[nf] + bet[nf];
        ws += wk[j] * y;
      }
      ws += __shfl_xor(ws, 16, 64);
      ws += __shfl_xor(ws, 32, 64);
      if (lh == 0)
        out_arg[(size_t)(bx * 4 + mf) * 1024 + wid * 64 + nf * 16 + lr] = ws;
    }
  }
}

// ---------------------------------------------------------------------------
extern "C" void kernel_launch(void* const* d_in, const int* in_sizes, int n_in,
                              void* d_out, int out_size, void* d_ws, size_t ws_size,
                              hipStream_t stream) {
  const float* token  = (const float*)d_in[0];
  const float* routed = (const float*)d_in[1];
  const float* simrow = (const float*)d_in[2];
  const float* delta  = (const float*)d_in[3];
  const float* Wl     = (const float*)d_in[4];
  const float* bl     = (const float*)d_in[5];
  const float* gamma  = (const float*)d_in[6];
  const float* beta   = (const float*)d_in[7];
  const float* Wg     = (const float*)d_in[8];
  const float* bg     = (const float*)d_in[9];

  char* ws = (char*)d_ws;
  ushort* Bmain = (ushort*)(ws);                         // 4 MB
  ushort* Bk1   = (ushort*)(ws + (4u << 20));            // 2 MB
  ushort* Bgate = (ushort*)(ws + (6u << 20));            // 4 MB
  float*  tpart = (float*)(ws + (10u << 20));            // 16 MB

  float* out_arg  = (float*)d_out;
  float* out_gate = out_arg + (size_t)4096 * 1024;

  prep_kernel<<<1280, 256, 0, stream>>>(Wl, Wg, Bmain, Bk1, Bgate);
  gemm_small<32, 32, 0><<<dim3(64, 8), 256, 0, stream>>>(
      token, token, Bk1, bl, tpart);
  main_kernel<<<1024, 1024, 0, stream>>>(
      routed, delta, simrow, Bmain, tpart, gamma, beta, out_arg);
  gemm_small<64, 32, 1><<<dim3(64, 8), 256, 0, stream>>>(
      token, out_arg, Bgate, bg, out_gate);
}

// Round 8
// 538.612 us; speedup vs baseline: 1.2907x; 1.1414x over previous
//
#include <hip/hip_runtime.h>
#include <hip/hip_bf16.h>

// Problem constants: D=1024, N=4096, K=16, M = N*K = 65536, K-dim main = 2048

typedef __attribute__((ext_vector_type(4))) float f32x4;
typedef __attribute__((ext_vector_type(8))) short bf16x8;

__device__ __forceinline__ ushort f2bf(float f) {
  unsigned b = __builtin_bit_cast(unsigned, f);
  b += 0x7FFFu + ((b >> 16) & 1u);   // RNE
  return (ushort)(b >> 16);
}
__device__ __forceinline__ unsigned pk2(float a, float b) {
  return (unsigned)f2bf(a) | ((unsigned)f2bf(b) << 16);
}

// LDS XOR swizzle for the A tile (verified in passing R1/R4/R6/R7 kernels)
__device__ __forceinline__ unsigned swz(unsigned a) {
  return a ^ (((a >> 7) & 3u) << 4);
}

__device__ __forceinline__ bf16x8 cvt8(const float* p) {
  f32x4 a = *(const f32x4*)p;
  f32x4 b = *(const f32x4*)(p + 4);
  bf16x8 r;
  r[0] = (short)f2bf(a[0]); r[1] = (short)f2bf(a[1]);
  r[2] = (short)f2bf(a[2]); r[3] = (short)f2bf(a[3]);
  r[4] = (short)f2bf(b[0]); r[5] = (short)f2bf(b[1]);
  r[6] = (short)f2bf(b[2]); r[7] = (short)f2bf(b[3]);
  return r;
}

// ---------------------------------------------------------------------------
// prep: LDS tile-transpose weight packer (verified green R4-R7).
// mode 0 (bid<512):  Bmain packed layout: flat = kt*32768 + wg*4096 + c*8 + m,
//                    chunk c = nf*64 + lane; value = Wl[1024+kt*32+(lane>>4)*8+m]
//                                                      [wg*128+nf*16+(lane&15)]
// mode 1 (512..768): Bk1 layout [kt][nn][q*8+m] from Wl rows 0..1023
// mode 2 (768..1280): Bgate same layout from Wg rows kt*32 (+ row+1024 summed
//                    when kt>=32)
// ---------------------------------------------------------------------------
__global__ __launch_bounds__(256) void prep_kernel(
    const float* __restrict__ Wl, const float* __restrict__ Wg,
    ushort* __restrict__ Bmain, ushort* __restrict__ Bk1,
    ushort* __restrict__ Bgate) {
  __shared__ float L[32][129];
  int t = threadIdx.x;
  int bid = blockIdx.x;
  const float* src; int row0, mode, kt, wg; ushort* dst;
  if (bid < 512)      { mode = 0; kt = bid >> 3;        wg = bid & 7; src = Wl; row0 = 1024 + kt * 32; dst = Bmain; }
  else if (bid < 768) { mode = 1; kt = (bid - 512) >> 3; wg = (bid - 512) & 7; src = Wl; row0 = kt * 32; dst = Bk1; }
  else                { mode = 2; kt = (bid - 768) >> 3; wg = (bid - 768) & 7; src = Wg; row0 = kt * 32; dst = Bgate; }
  int col0 = wg * 128;
  bool dosum = (mode == 2) && (kt >= 32);
#pragma unroll
  for (int p = 0; p < 4; ++p) {
    int r = p * 8 + (t >> 5), c = (t & 31) * 4;
    const float* sp = src + (size_t)(row0 + r) * 1024 + col0 + c;
    f32x4 v = *(const f32x4*)sp;
    if (dosum) { f32x4 v2 = *(const f32x4*)(sp + (size_t)1024 * 1024); v += v2; }
    L[r][c] = v[0]; L[r][c + 1] = v[1]; L[r][c + 2] = v[2]; L[r][c + 3] = v[3];
  }
  __syncthreads();
  if (mode == 0) {
    for (int c = t; c < 512; c += 256) {
      int nf = c >> 6, lane = c & 63, lr_ = lane & 15, lh_ = lane >> 4;
      bf16x8 o;
#pragma unroll
      for (int m = 0; m < 8; ++m) o[m] = (short)f2bf(L[lh_ * 8 + m][nf * 16 + lr_]);
      *(bf16x8*)(dst + (size_t)kt * 32768 + wg * 4096 + c * 8) = o;
    }
  } else {
    for (int c = t; c < 512; c += 256) {
      int nn = c >> 2, q = c & 3;
      bf16x8 o;
#pragma unroll
      for (int m = 0; m < 8; ++m) o[m] = (short)f2bf(L[q * 8 + m][nn]);
      *(bf16x8*)(dst + (size_t)kt * 32768 + (size_t)(wg * 128 + nn) * 32 + q * 8) = o;
    }
  }
}

// ---------------------------------------------------------------------------
// gemm_small: C = act(A_f32 @ Bpack + bias). 64x128 tile, 4 waves (2x2),
// wave tile 32x64. grid (M/64, 8) = 512 blocks -> 2 blocks/CU. (green)
// ---------------------------------------------------------------------------
template <int NKT, int NSPLIT, int ACT>
__global__ __launch_bounds__(256) void gemm_small(
    const float* __restrict__ A0, const float* __restrict__ A1,
    const ushort* __restrict__ Bp, const float* __restrict__ bias,
    float* __restrict__ Cout) {
  int tid = threadIdx.x, l = tid & 63, wid = tid >> 6;
  int wm = wid & 1, wn = wid >> 1;
  int mbase = blockIdx.x * 64 + wm * 32;
  int nbase = blockIdx.y * 128 + wn * 64;
  int lr = l & 15, lh = l >> 4;
  f32x4 acc[2][4] = {};
#pragma unroll 1
  for (int kt = 0; kt < NKT; ++kt) {
    const float* As = (kt < NSPLIT) ? A0 : A1;
    int ke = ((kt < NSPLIT) ? kt : kt - NSPLIT) * 32 + lh * 8;
    bf16x8 af[2];
#pragma unroll
    for (int mf = 0; mf < 2; ++mf)
      af[mf] = cvt8(As + (size_t)(mbase + mf * 16 + lr) * 1024 + ke);
    bf16x8 bf[4];
#pragma unroll
    for (int nf = 0; nf < 4; ++nf)
      bf[nf] = *(const bf16x8*)(Bp + (size_t)kt * 32768 +
                                (size_t)(nbase + nf * 16 + lr) * 32 + lh * 8);
#pragma unroll
    for (int nf = 0; nf < 4; ++nf)
#pragma unroll
      for (int mf = 0; mf < 2; ++mf)
        acc[mf][nf] = __builtin_amdgcn_mfma_f32_16x16x32_bf16(
            af[mf], bf[nf], acc[mf][nf], 0, 0, 0);
  }
#pragma unroll
  for (int nf = 0; nf < 4; ++nf) {
    int col = nbase + nf * 16 + lr;
    float bs = bias[col];
#pragma unroll
    for (int mf = 0; mf < 2; ++mf)
#pragma unroll
      for (int j = 0; j < 4; ++j) {
        int row = mbase + mf * 16 + lh * 4 + j;
        float v = acc[mf][nf][j] + bs;
        if (ACT == 1) v = 1.0f / (1.0f + expf(-v));
        Cout[(size_t)row * 1024 + col] = v;
      }
  }
}

// ---------------------------------------------------------------------------
// main fused kernel — R7 skeleton (16 waves x 64x64, acc[4][4]) with a
// register-double-buffered B pipeline (2-step unrolled, named bfA/bfB per
// rule #20): B(kt+1) loads fly to VGPRs while MFMAs consume B(kt). VGPR
// loads are NOT drained by __syncthreads (no LDS interaction), so they
// genuinely span the barrier — this breaks the serialized per-iteration
// {B-latency -> MFMA -> barrier} chain measured at 4940 cy/iter in R4-R7.
// A: f32 global -> reg -> cvt bf16 -> swizzled 4KB LDS tile, dbuf (Ab0/Ab1),
//    1024 threads x 4B, 1 iteration ahead (HBM latency under MFMA phase).
// Epilogue: +t_part, exact GELU, LayerNorm (16-wave LDS reduce),
// softmax-weighted K-reduce -> arg_summary. (unchanged, green)
// ---------------------------------------------------------------------------
#define MFMA_STEP(ABSYM, BF) do {                                         \
  bf16x8 af_[4];                                                          \
  _Pragma("unroll")                                                       \
  for (int mf = 0; mf < 4; ++mf)                                          \
    af_[mf] = *(const bf16x8*)((const char*)(ABSYM) + aoff[mf]);          \
  _Pragma("unroll")                                                       \
  for (int nf = 0; nf < 4; ++nf)                                          \
    _Pragma("unroll")                                                     \
    for (int mf = 0; mf < 4; ++mf)                                        \
      acc[mf][nf] = __builtin_amdgcn_mfma_f32_16x16x32_bf16(              \
          af_[mf], (BF)[nf], acc[mf][nf], 0, 0, 0);                       \
} while (0)

__global__ __launch_bounds__(1024) void main_kernel(
    const float* __restrict__ routed, const float* __restrict__ delta,
    const float* __restrict__ simrow, const ushort* __restrict__ Bmain,
    const float* __restrict__ tpart, const float* __restrict__ gamma,
    const float* __restrict__ beta, float* __restrict__ out_arg) {
  __shared__ ushort Ab0[2048];          // 4KB A tile [64][32] bf16 (swz)
  __shared__ ushort Ab1[2048];
  __shared__ float ldsW[64];            // softmax weights 4 tokens x 16 k
  __shared__ float lnS[64 * 16], lnQ[64 * 16];

  int tid = threadIdx.x, l = tid & 63, wid = tid >> 6;   // wid 0..15
  int bx = blockIdx.x;                  // tokens bx*4 .. bx*4+3
  int lr = l & 15, lh = l >> 4;

  if (tid < 4) {                        // softmax over K=16 for token bx*4+tid
    int n = bx * 4 + tid;
    float sv[16], mx = -1e30f;
#pragma unroll
    for (int j = 0; j < 16; ++j) { sv[j] = simrow[n * 16 + j]; mx = fmaxf(mx, sv[j]); }
    float s = 0.f;
#pragma unroll
    for (int j = 0; j < 16; ++j) { sv[j] = expf(sv[j] - mx); s += sv[j]; }
    float inv = 1.0f / s;
#pragma unroll
    for (int j = 0; j < 16; ++j) ldsW[tid * 16 + j] = sv[j] * inv;
  }

  // A staging geometry: 1024 threads x 4B of the 4KB tile.
  const int arow = tid >> 4;
  const float* rbase = routed + (size_t)(bx * 64 + arow) * 1024 + (tid & 15) * 2;
  const float* dbase = delta  + (size_t)(bx * 64 + arow) * 1024 + (tid & 15) * 2;
  const unsigned adst = swz((unsigned)tid * 4);

  // A-tile read offsets (loop-invariant, swizzled)
  unsigned aoff[4];
#pragma unroll
  for (int mf = 0; mf < 4; ++mf)
    aoff[mf] = swz((unsigned)(mf * 16 + lr) * 64 + (unsigned)lh * 16);

  // B per-lane pointer: wave wid covers cols wid*64 + nf*16 + lr.
  // packed: wg = wid>>1, chunk = ((wid&1)*4+nf)*64 + l -> 16B/lane coalesced
  const ushort* bptr = Bmain + (size_t)(wid >> 1) * 4096 +
                       (size_t)(wid & 1) * 2048 + (size_t)l * 8;

  // ---- prologue: A(0)->Ab0, B(0)->bfA, A(1)->avA ----
  {
    float2 v = *(const float2*)rbase;
    *(unsigned*)((char*)Ab0 + adst) = pk2(v.x, v.y);
  }
  bf16x8 bfA[4], bfB[4];
#pragma unroll
  for (int nf = 0; nf < 4; ++nf)
    bfA[nf] = *(const bf16x8*)(bptr + nf * 512);
  float2 avA = *(const float2*)(rbase + 32);
  float2 avB;
  __syncthreads();

  f32x4 acc[4][4] = {};
#pragma unroll 1
  for (int kt = 0; kt < 64; kt += 2) {
    // ===== even step: consume Ab0 + bfA =====
#pragma unroll
    for (int nf = 0; nf < 4; ++nf)       // B(kt+1) in flight during MFMAs
      bfB[nf] = *(const bf16x8*)(bptr + 32768 + nf * 512);
    {                                    // A(kt+2) in flight
      const float* as_ = (kt + 2 < 32) ? rbase : dbase;
      avB = *(const float2*)(as_ + (size_t)((kt + 2) & 31) * 32);
    }
    MFMA_STEP(Ab0, bfA);
    *(unsigned*)((char*)Ab1 + adst) = pk2(avA.x, avA.y);   // A(kt+1)->Ab1
    __syncthreads();
    // ===== odd step: consume Ab1 + bfB =====
#pragma unroll
    for (int nf = 0; nf < 4; ++nf)       // B(kt+2) (benign over-read at end)
      bfA[nf] = *(const bf16x8*)(bptr + 65536 + nf * 512);
    {                                    // A(kt+3) (benign over-read at end)
      const float* as_ = (kt + 3 < 32) ? rbase : dbase;
      avA = *(const float2*)(as_ + (size_t)((kt + 3) & 31) * 32);
    }
    MFMA_STEP(Ab1, bfB);
    *(unsigned*)((char*)Ab0 + adst) = pk2(avB.x, avB.y);   // A(kt+2)->Ab0
    __syncthreads();
    bptr += 65536;
  }

  // ---- fused epilogue (unchanged, green) ----
  // acc[mf][nf][j]: local row mf*16 + lh*4 + j (= token mf, k = lh*4+j),
  //                 col wid*64 + nf*16 + lr
  const float inv_d = 1.0f / 1024.0f;
  float gam[4], bet[4];
#pragma unroll
  for (int nf = 0; nf < 4; ++nf) {
    int c = wid * 64 + nf * 16 + lr;
    gam[nf] = gamma[c]; bet[nf] = beta[c];
  }
#pragma unroll
  for (int mf = 0; mf < 4; ++mf) {
    int tokrow = bx * 4 + mf;
    float s[4] = {0, 0, 0, 0}, q[4] = {0, 0, 0, 0};
#pragma unroll
    for (int nf = 0; nf < 4; ++nf) {
      float tp = tpart[(size_t)tokrow * 1024 + wid * 64 + nf * 16 + lr];
#pragma unroll
      for (int j = 0; j < 4; ++j) {
        float h = acc[mf][nf][j] + tp;
        float g = 0.5f * h * (1.0f + erff(h * 0.70710678118654752f));
        acc[mf][nf][j] = g;
        s[j] += g; q[j] += g * g;
      }
    }
#pragma unroll
    for (int j = 0; j < 4; ++j) {
#pragma unroll
      for (int d = 1; d <= 8; d <<= 1) {
        s[j] += __shfl_xor(s[j], d, 64);
        q[j] += __shfl_xor(q[j], d, 64);
      }
    }
    if (lr == 0) {
#pragma unroll
      for (int j = 0; j < 4; ++j) {
        int row = mf * 16 + lh * 4 + j;
        lnS[row * 16 + wid] = s[j];
        lnQ[row * 16 + wid] = q[j];
      }
    }
  }
  __syncthreads();
#pragma unroll
  for (int mf = 0; mf < 4; ++mf) {
    float mu[4], rs[4], wk[4];
#pragma unroll
    for (int j = 0; j < 4; ++j) {
      int row = mf * 16 + lh * 4 + j;
      float S = 0.f, Q = 0.f;
#pragma unroll
      for (int w4 = 0; w4 < 4; ++w4) {
        f32x4 vs = *(const f32x4*)&lnS[row * 16 + w4 * 4];
        f32x4 vq = *(const f32x4*)&lnQ[row * 16 + w4 * 4];
        S += vs[0] + vs[1] + vs[2] + vs[3];
        Q += vq[0] + vq[1] + vq[2] + vq[3];
      }
      float m_ = S * inv_d;
      mu[j] = m_;
      rs[j] = rsqrtf(Q * inv_d - m_ * m_ + 1e-5f);
      wk[j] = ldsW[row];
    }
#pragma unroll
    for (int nf = 0; nf < 4; ++nf) {
      float ws = 0.f;
#pragma unroll
      for (int j = 0; j < 4; ++j) {
        float y = (acc[mf][nf][j] - mu[j]) * rs[j] * gam[nf] + bet[nf];
        ws += wk[j] * y;
      }
      ws += __shfl_xor(ws, 16, 64);
      ws += __shfl_xor(ws, 32, 64);
      if (lh == 0)
        out_arg[(size_t)(bx * 4 + mf) * 1024 + wid * 64 + nf * 16 + lr] = ws;
    }
  }
}

// ---------------------------------------------------------------------------
extern "C" void kernel_launch(void* const* d_in, const int* in_sizes, int n_in,
                              void* d_out, int out_size, void* d_ws, size_t ws_size,
                              hipStream_t stream) {
  const float* token  = (const float*)d_in[0];
  const float* routed = (const float*)d_in[1];
  const float* simrow = (const float*)d_in[2];
  const float* delta  = (const float*)d_in[3];
  const float* Wl     = (const float*)d_in[4];
  const float* bl     = (const float*)d_in[5];
  const float* gamma  = (const float*)d_in[6];
  const float* beta   = (const float*)d_in[7];
  const float* Wg     = (const float*)d_in[8];
  const float* bg     = (const float*)d_in[9];

  char* ws = (char*)d_ws;
  ushort* Bmain = (ushort*)(ws);                         // 4 MB
  ushort* Bk1   = (ushort*)(ws + (4u << 20));            // 2 MB
  ushort* Bgate = (ushort*)(ws + (6u << 20));            // 4 MB
  float*  tpart = (float*)(ws + (10u << 20));            // 16 MB

  float* out_arg  = (float*)d_out;
  float* out_gate = out_arg + (size_t)4096 * 1024;

  prep_kernel<<<1280, 256, 0, stream>>>(Wl, Wg, Bmain, Bk1, Bgate);
  gemm_small<32, 32, 0><<<dim3(64, 8), 256, 0, stream>>>(
      token, token, Bk1, bl, tpart);
  main_kernel<<<1024, 1024, 0, stream>>>(
      routed, delta, simrow, Bmain, tpart, gamma, beta, out_arg);
  gemm_small<64, 32, 1><<<dim3(64, 8), 256, 0, stream>>>(
      token, out_arg, Bgate, bg, out_gate);
}